// Round 2
// baseline (602.889 us; speedup 1.0000x reference)
//
#include <hip/hip_runtime.h>
#include <hip/hip_bf16.h>

#define B_TOK 2048
#define D_DIM 1024
#define E_NUM 8
#define H_DIM 4096
#define C_DIM 1024
#define CAP   5120
#define MAXT  40

typedef __attribute__((ext_vector_type(8))) short bf16x8;
typedef __attribute__((ext_vector_type(4))) float floatx4;

__device__ __forceinline__ unsigned short f2bf(float f) {
  union { float f; unsigned int u; } a; a.f = f;
  unsigned int u = a.u;
  return (unsigned short)((u + 0x7FFFu + ((u >> 16) & 1u)) >> 16);
}

__device__ __forceinline__ void gload_lds16(const void* g, void* l) {
  __builtin_amdgcn_global_load_lds(
      (const __attribute__((address_space(1))) void*)g,
      (__attribute__((address_space(3))) void*)l, 16, 0, 0);
}

// ---------------- init: zero out_acc, counts, slot_tok = -1 ----------------
__global__ __launch_bounds__(256) void kinit(float* out_acc, int* slot_tok, int* counts) {
  int id = blockIdx.x * 256 + threadIdx.x;   // grid sized exactly B_TOK*C_DIM
  out_acc[id] = 0.f;
  if (id < CAP) slot_tok[id] = -1;
  if (id < E_NUM) counts[id] = 0;
}

// ---------------- router: logits, top2, softmax, LN stats ----------------
__global__ __launch_bounds__(256) void krouter(const float* __restrict__ x,
                                               const float* __restrict__ Wr,
                                               const float* __restrict__ br,
                                               int2* meta_i, float4* meta_f, int* counts) {
  int b = blockIdx.x, t = threadIdx.x;
  const float4 xv = *(const float4*)(x + (size_t)b * D_DIM + t * 4);
  float v[10];
  v[0] = xv.x + xv.y + xv.z + xv.w;
  v[1] = xv.x * xv.x + xv.y * xv.y + xv.z * xv.z + xv.w * xv.w;
#pragma unroll
  for (int e = 0; e < 8; e++) v[2 + e] = 0.f;
  const float* wr = Wr + (size_t)(t * 4) * E_NUM;
  float xs[4] = {xv.x, xv.y, xv.z, xv.w};
#pragma unroll
  for (int j = 0; j < 4; j++) {
    float4 wa = *(const float4*)(wr + j * 8);
    float4 wb = *(const float4*)(wr + j * 8 + 4);
    v[2] += xs[j] * wa.x; v[3] += xs[j] * wa.y; v[4] += xs[j] * wa.z; v[5] += xs[j] * wa.w;
    v[6] += xs[j] * wb.x; v[7] += xs[j] * wb.y; v[8] += xs[j] * wb.z; v[9] += xs[j] * wb.w;
  }
#pragma unroll
  for (int i = 0; i < 10; i++) {
    float s = v[i];
#pragma unroll
    for (int off = 32; off > 0; off >>= 1) s += __shfl_down(s, off, 64);
    v[i] = s;
  }
  __shared__ float red[4][10];
  int lane = t & 63, wid = t >> 6;
  if (lane == 0) {
#pragma unroll
    for (int i = 0; i < 10; i++) red[wid][i] = v[i];
  }
  __syncthreads();
  if (t == 0) {
    float f[10];
#pragma unroll
    for (int i = 0; i < 10; i++) f[i] = red[0][i] + red[1][i] + red[2][i] + red[3][i];
    float mu = f[0] * (1.f / 1024.f);
    float var = f[1] * (1.f / 1024.f) - mu * mu;
    float rsig = rsqrtf(var + 1e-5f);
    float lg[8];
#pragma unroll
    for (int e = 0; e < 8; e++) lg[e] = f[2 + e] + br[e];
    int i0 = 0;
#pragma unroll
    for (int e = 1; e < 8; e++) if (lg[e] > lg[i0]) i0 = e;
    int i1 = (i0 == 0) ? 1 : 0;
#pragma unroll
    for (int e = 0; e < 8; e++) if (e != i0 && lg[e] > lg[i1]) i1 = e;
    float ex = expf(lg[i1] - lg[i0]);       // <= 1
    float w0 = 1.f / (1.f + ex);
    float w1 = 1.f - w0;
    atomicAdd(counts + i0, 1);
    atomicAdd(counts + i1, 1);
    meta_i[b] = make_int2(i0, i1);
    meta_f[b] = make_float4(w0, w1, mu, rsig);
  }
}

// ---------------- prefix: 128-aligned segments + tile map ----------------
__global__ void kprefix(const int* counts, int* cursor, int* tmap_e, int* tmap_r) {
  if (threadIdx.x == 0) {
    int total = 0, tt = 0;
    for (int e = 0; e < E_NUM; e++) {
      cursor[e] = total;
      int nt = (counts[e] + 127) >> 7;
      for (int i = 0; i < nt; i++) { tmap_e[tt] = e; tmap_r[tt] = total + i * 128; tt++; }
      total += nt << 7;
    }
    for (; tt < MAXT; tt++) tmap_e[tt] = -1;
  }
}

// ---------------- scatter: slot assign + xe (bf16) ----------------
__global__ __launch_bounds__(256) void kscatter(const float* __restrict__ x,
                                                const float* __restrict__ ln_g,
                                                const float* __restrict__ ln_b,
                                                const int2* __restrict__ meta_i,
                                                const float4* __restrict__ meta_f,
                                                int* cursor, int* slot_tok, float* slot_w,
                                                unsigned short* __restrict__ xe) {
  int b = blockIdx.x, t = threadIdx.x;
  __shared__ int se[2], ss[2];
  __shared__ float smu, srs;
  if (t == 0) {
    int2 mi = meta_i[b];
    float4 mf = meta_f[b];
    int s0 = atomicAdd(cursor + mi.x, 1);
    int s1 = atomicAdd(cursor + mi.y, 1);
    slot_tok[s0] = b; slot_w[s0] = mf.x;
    slot_tok[s1] = b; slot_w[s1] = mf.y;
    se[0] = mi.x; se[1] = mi.y; ss[0] = s0; ss[1] = s1;
    smu = mf.z; srs = mf.w;
  }
  __syncthreads();
  int i = t * 4;
  float4 xv = *(const float4*)(x + (size_t)b * D_DIM + i);
  float mu = smu, rs = srs;
  float xn0 = (xv.x - mu) * rs, xn1 = (xv.y - mu) * rs, xn2 = (xv.z - mu) * rs, xn3 = (xv.w - mu) * rs;
#pragma unroll
  for (int k = 0; k < 2; k++) {
    int e = se[k], s = ss[k];
    float4 g = *(const float4*)(ln_g + (size_t)e * D_DIM + i);
    float4 bb = *(const float4*)(ln_b + (size_t)e * D_DIM + i);
    union { unsigned short us[4]; uint2 v; } u;
    u.us[0] = f2bf(xn0 * g.x + bb.x);
    u.us[1] = f2bf(xn1 * g.y + bb.y);
    u.us[2] = f2bf(xn2 * g.z + bb.z);
    u.us[3] = f2bf(xn3 * g.w + bb.w);
    *(uint2*)(xe + (size_t)s * D_DIM + i) = u.v;
  }
}

// ---------------- transpose+convert: src f32 [z][R][C] -> dst bf16 [z][C][R] ----------------
__global__ __launch_bounds__(256) void ktranspose(const float* __restrict__ src,
                                                  unsigned short* __restrict__ dst,
                                                  int R, int C) {
  __shared__ float tile[64][65];
  int z = blockIdx.z;
  const float* s = src + (size_t)z * R * C;
  unsigned short* d = dst + (size_t)z * R * C;
  int cx = blockIdx.x * 64, ry = blockIdx.y * 64;
  int t = threadIdx.x;
  int cl4 = (t & 15) * 4, rl = t >> 4;
#pragma unroll
  for (int p = 0; p < 4; p++) {
    int r = rl + p * 16;
    float4 v = *(const float4*)(s + (size_t)(ry + r) * C + cx + cl4);
    tile[r][cl4] = v.x; tile[r][cl4 + 1] = v.y; tile[r][cl4 + 2] = v.z; tile[r][cl4 + 3] = v.w;
  }
  __syncthreads();
#pragma unroll
  for (int p = 0; p < 4; p++) {
    int c = rl + p * 16;   // src col -> dst row
    union { unsigned short us[4]; uint2 v; } u;
    u.us[0] = f2bf(tile[cl4][c]);
    u.us[1] = f2bf(tile[cl4 + 1][c]);
    u.us[2] = f2bf(tile[cl4 + 2][c]);
    u.us[3] = f2bf(tile[cl4 + 3][c]);
    *(uint2*)(d + (size_t)(cx + c) * R + ry + cl4) = u.v;
  }
}

// ---------------- GEMM1: h = gelu(xe @ W1[e] + b1[e]), bf16 out ----------------
// 128x128 tile, BK=32, double-buffered LDS with stage-early (T3-min),
// XOR-swizzled LDS (pre-swizzled global source + swizzled ds_read), XCD swizzle.
__global__ __launch_bounds__(256) void kgemm1(const unsigned short* __restrict__ xe,
                                              const unsigned short* __restrict__ w1t,
                                              const float* __restrict__ b1,
                                              unsigned short* __restrict__ h,
                                              const int* __restrict__ tmap_e,
                                              const int* __restrict__ tmap_r) {
  // bijective XCD chunk remap: nwg = 32*40 = 1280, 1280/8 = 160
  int orig = blockIdx.y * 32 + blockIdx.x;
  int s = (orig & 7) * 160 + (orig >> 3);
  int bx = s & 31, by = s >> 5;
  int e = tmap_e[by];
  if (e < 0) return;
  int row0 = tmap_r[by];
  int n0 = bx * 128;
  const unsigned short* Ab = xe + (size_t)row0 * D_DIM;
  const unsigned short* Bb = w1t + (size_t)e * H_DIM * D_DIM + (size_t)n0 * D_DIM;
  __shared__ unsigned short As[2][128 * 32];
  __shared__ unsigned short Bs[2][128 * 32];
  int t = threadIdx.x, lane = t & 63, wid = t >> 6;
  int c0 = wid * 2, c1 = c0 + 1;
  int lr = lane >> 2;
  // source pre-swizzle: LDS slot (row, chunk=lane&3) receives global chunk (lane&3)^g(row),
  // g(row) = (row>>1)&3 = (lane>>3)&3 for row = cg*16 + (lane>>2)
  int kc = ((lane & 3) ^ ((lane >> 3) & 3)) * 8;
  const unsigned short* ga0 = Ab + (size_t)(c0 * 16 + lr) * D_DIM + kc;
  const unsigned short* ga1 = ga0 + 16 * D_DIM;
  const unsigned short* gb0 = Bb + (size_t)(c0 * 16 + lr) * D_DIM + kc;
  const unsigned short* gb1 = gb0 + 16 * D_DIM;
  int l15 = lane & 15, q = lane >> 4;
  int wm = (wid & 1) * 64, wn = (wid >> 1) * 64;
  int offA[4], offB[4];
#pragma unroll
  for (int i = 0; i < 4; i++) {
    int ra = wm + i * 16 + l15;
    int rb = wn + i * 16 + l15;
    offA[i] = ra * 32 + ((q ^ ((ra >> 1) & 3)) * 8);   // read-side swizzle (same XOR)
    offB[i] = rb * 32 + ((q ^ ((rb >> 1) & 3)) * 8);
  }
  floatx4 acc[4][4];
#pragma unroll
  for (int i = 0; i < 4; i++)
#pragma unroll
    for (int j = 0; j < 4; j++) acc[i][j] = (floatx4){0.f, 0.f, 0.f, 0.f};

#define G1_STAGE(bsel)                              \
  do {                                              \
    gload_lds16(ga0, &As[bsel][c0 * 512]);          \
    gload_lds16(ga1, &As[bsel][c1 * 512]);          \
    gload_lds16(gb0, &Bs[bsel][c0 * 512]);          \
    gload_lds16(gb1, &Bs[bsel][c1 * 512]);          \
    ga0 += 32; ga1 += 32; gb0 += 32; gb1 += 32;     \
  } while (0)

#define G1_COMPUTE(bsel)                                                    \
  do {                                                                      \
    bf16x8 af[4], bfr[4];                                                   \
    _Pragma("unroll") for (int i = 0; i < 4; i++) {                         \
      af[i] = *(const bf16x8*)(&As[bsel][offA[i]]);                         \
      bfr[i] = *(const bf16x8*)(&Bs[bsel][offB[i]]);                        \
    }                                                                       \
    _Pragma("unroll") for (int mt = 0; mt < 4; mt++)                        \
      _Pragma("unroll") for (int nt = 0; nt < 4; nt++)                      \
        acc[mt][nt] = __builtin_amdgcn_mfma_f32_16x16x32_bf16(af[mt], bfr[nt], acc[mt][nt], 0, 0, 0); \
  } while (0)

  G1_STAGE(0);
  __syncthreads();
#pragma unroll 1
  for (int it = 0; it < D_DIM / 64 - 1; it++) {
    G1_STAGE(1);
    G1_COMPUTE(0);
    __syncthreads();
    G1_STAGE(0);
    G1_COMPUTE(1);
    __syncthreads();
  }
  G1_STAGE(1);
  G1_COMPUTE(0);
  __syncthreads();
  G1_COMPUTE(1);
#undef G1_STAGE
#undef G1_COMPUTE

  float b1v[4];
#pragma unroll
  for (int nt = 0; nt < 4; nt++) b1v[nt] = b1[(size_t)e * H_DIM + n0 + wn + nt * 16 + l15];
#pragma unroll
  for (int mt = 0; mt < 4; mt++) {
    int row = row0 + wm + mt * 16 + q * 4;
#pragma unroll
    for (int nt = 0; nt < 4; nt++) {
      int col = n0 + wn + nt * 16 + l15;
      unsigned short* hp = h + (size_t)row * H_DIM + col;
#pragma unroll
      for (int r = 0; r < 4; r++) {
        float v = acc[mt][nt][r] + b1v[nt];
        v = 0.5f * v * (1.f + erff(v * 0.70710678118f));
        hp[(size_t)r * H_DIM] = f2bf(v);
      }
    }
  }
}

// ---------------- GEMM2: out_acc[token] += w * (h @ W2[e]) ----------------
// same structure as kgemm1; kz=4 K-split for occupancy (grid 8x40x4 = 1280 blocks)
__global__ __launch_bounds__(256) void kgemm2(const unsigned short* __restrict__ h,
                                              const unsigned short* __restrict__ w2t,
                                              const int* __restrict__ slot_tok,
                                              const float* __restrict__ slot_w,
                                              float* __restrict__ out_acc,
                                              const int* __restrict__ tmap_e,
                                              const int* __restrict__ tmap_r) {
  // bijective XCD chunk remap: nwg = 8*40*4 = 1280, 1280/8 = 160
  int orig = (blockIdx.z * MAXT + blockIdx.y) * 8 + blockIdx.x;
  int s = (orig & 7) * 160 + (orig >> 3);
  int bx = s & 7;
  int rest = s >> 3;
  int by = rest % MAXT;
  int kz = rest / MAXT;
  int e = tmap_e[by];
  if (e < 0) return;
  int row0 = tmap_r[by];
  int n0 = bx * 128;
  const unsigned short* Ab = h + (size_t)row0 * H_DIM + kz * 1024;
  const unsigned short* Bb = w2t + (size_t)e * C_DIM * H_DIM + (size_t)n0 * H_DIM + kz * 1024;
  __shared__ unsigned short As[2][128 * 32];
  __shared__ unsigned short Bs[2][128 * 32];
  __shared__ int stok[128];
  __shared__ float swgt[128];
  int t = threadIdx.x, lane = t & 63, wid = t >> 6;
  if (t < 128) { stok[t] = slot_tok[row0 + t]; swgt[t] = slot_w[row0 + t]; }
  int c0 = wid * 2, c1 = c0 + 1;
  int lr = lane >> 2;
  int kc = ((lane & 3) ^ ((lane >> 3) & 3)) * 8;
  const unsigned short* ga0 = Ab + (size_t)(c0 * 16 + lr) * H_DIM + kc;
  const unsigned short* ga1 = ga0 + (size_t)16 * H_DIM;
  const unsigned short* gb0 = Bb + (size_t)(c0 * 16 + lr) * H_DIM + kc;
  const unsigned short* gb1 = gb0 + (size_t)16 * H_DIM;
  int l15 = lane & 15, q = lane >> 4;
  int wm = (wid & 1) * 64, wn = (wid >> 1) * 64;
  int offA[4], offB[4];
#pragma unroll
  for (int i = 0; i < 4; i++) {
    int ra = wm + i * 16 + l15;
    int rb = wn + i * 16 + l15;
    offA[i] = ra * 32 + ((q ^ ((ra >> 1) & 3)) * 8);
    offB[i] = rb * 32 + ((q ^ ((rb >> 1) & 3)) * 8);
  }
  floatx4 acc[4][4];
#pragma unroll
  for (int i = 0; i < 4; i++)
#pragma unroll
    for (int j = 0; j < 4; j++) acc[i][j] = (floatx4){0.f, 0.f, 0.f, 0.f};

#define G2_STAGE(bsel)                              \
  do {                                              \
    gload_lds16(ga0, &As[bsel][c0 * 512]);          \
    gload_lds16(ga1, &As[bsel][c1 * 512]);          \
    gload_lds16(gb0, &Bs[bsel][c0 * 512]);          \
    gload_lds16(gb1, &Bs[bsel][c1 * 512]);          \
    ga0 += 32; ga1 += 32; gb0 += 32; gb1 += 32;     \
  } while (0)

#define G2_COMPUTE(bsel)                                                    \
  do {                                                                      \
    bf16x8 af[4], bfr[4];                                                   \
    _Pragma("unroll") for (int i = 0; i < 4; i++) {                         \
      af[i] = *(const bf16x8*)(&As[bsel][offA[i]]);                         \
      bfr[i] = *(const bf16x8*)(&Bs[bsel][offB[i]]);                        \
    }                                                                       \
    _Pragma("unroll") for (int mt = 0; mt < 4; mt++)                        \
      _Pragma("unroll") for (int nt = 0; nt < 4; nt++)                      \
        acc[mt][nt] = __builtin_amdgcn_mfma_f32_16x16x32_bf16(af[mt], bfr[nt], acc[mt][nt], 0, 0, 0); \
  } while (0)

  G2_STAGE(0);
  __syncthreads();
#pragma unroll 1
  for (int it = 0; it < 1024 / 64 - 1; it++) {
    G2_STAGE(1);
    G2_COMPUTE(0);
    __syncthreads();
    G2_STAGE(0);
    G2_COMPUTE(1);
    __syncthreads();
  }
  G2_STAGE(1);
  G2_COMPUTE(0);
  __syncthreads();
  G2_COMPUTE(1);
#undef G2_STAGE
#undef G2_COMPUTE

#pragma unroll
  for (int mt = 0; mt < 4; mt++) {
    int rbase = wm + mt * 16 + q * 4;
#pragma unroll
    for (int nt = 0; nt < 4; nt++) {
      int col = n0 + wn + nt * 16 + l15;
#pragma unroll
      for (int r = 0; r < 4; r++) {
        int tk = stok[rbase + r];
        if (tk >= 0)
          atomicAdd(out_acc + (size_t)tk * C_DIM + col, swgt[rbase + r] * acc[mt][nt][r]);
      }
    }
  }
}

// ---------------- final: out = f32(out_acc + w0*b2[e0] + w1*b2[e1]) ----------------
__global__ __launch_bounds__(256) void kfinal(const float* __restrict__ out_acc,
                                              const int2* __restrict__ meta_i,
                                              const float4* __restrict__ meta_f,
                                              const float* __restrict__ b2,
                                              float* __restrict__ out) {
  int b = blockIdx.x, t = threadIdx.x;
  int i = t * 4;
  int2 mi = meta_i[b];
  float4 mf = meta_f[b];
  float4 a = *(const float4*)(out_acc + (size_t)b * C_DIM + i);
  float4 p = *(const float4*)(b2 + (size_t)mi.x * C_DIM + i);
  float4 qv = *(const float4*)(b2 + (size_t)mi.y * C_DIM + i);
  float4 o;
  o.x = a.x + mf.x * p.x + mf.y * qv.x;
  o.y = a.y + mf.x * p.y + mf.y * qv.y;
  o.z = a.z + mf.x * p.z + mf.y * qv.z;
  o.w = a.w + mf.x * p.w + mf.y * qv.w;
  *(float4*)(out + (size_t)b * C_DIM + i) = o;
}

extern "C" void kernel_launch(void* const* d_in, const int* in_sizes, int n_in,
                              void* d_out, int out_size, void* d_ws, size_t ws_size,
                              hipStream_t stream) {
  const float* x    = (const float*)d_in[0];
  const float* Wr   = (const float*)d_in[1];
  const float* br   = (const float*)d_in[2];
  const float* ln_g = (const float*)d_in[3];
  const float* ln_b = (const float*)d_in[4];
  const float* W1   = (const float*)d_in[5];
  const float* b1   = (const float*)d_in[6];
  const float* W2   = (const float*)d_in[7];
  const float* b2   = (const float*)d_in[8];

  char* w = (char*)d_ws;
  auto alloc = [&](size_t sz) { char* p = w; w += (sz + 255) & ~(size_t)255; return p; };
  unsigned short* W1t = (unsigned short*)alloc((size_t)E_NUM * H_DIM * D_DIM * 2);
  unsigned short* W2t = (unsigned short*)alloc((size_t)E_NUM * C_DIM * H_DIM * 2);
  unsigned short* xe  = (unsigned short*)alloc((size_t)CAP * D_DIM * 2);
  unsigned short* hb  = (unsigned short*)alloc((size_t)CAP * H_DIM * 2);
  float* out_acc      = (float*)alloc((size_t)B_TOK * C_DIM * 4);
  int2* meta_i        = (int2*)alloc((size_t)B_TOK * 8);
  float4* meta_f      = (float4*)alloc((size_t)B_TOK * 16);
  int* counts         = (int*)alloc(64);
  int* cursor         = (int*)alloc(64);
  int* tmap_e         = (int*)alloc(MAXT * 4);
  int* tmap_r         = (int*)alloc(MAXT * 4);
  int* slot_tok       = (int*)alloc(CAP * 4);
  float* slot_w       = (float*)alloc(CAP * 4);

  // transposes first (longest; independent of routing)
  hipLaunchKernelGGL(ktranspose, dim3(H_DIM / 64, D_DIM / 64, E_NUM), dim3(256), 0, stream,
                     W1, W1t, D_DIM, H_DIM);
  hipLaunchKernelGGL(ktranspose, dim3(C_DIM / 64, H_DIM / 64, E_NUM), dim3(256), 0, stream,
                     W2, W2t, H_DIM, C_DIM);
  hipLaunchKernelGGL(kinit, dim3(B_TOK * C_DIM / 256), dim3(256), 0, stream,
                     out_acc, slot_tok, counts);
  hipLaunchKernelGGL(krouter, dim3(B_TOK), dim3(256), 0, stream,
                     x, Wr, br, meta_i, meta_f, counts);
  hipLaunchKernelGGL(kprefix, dim3(1), dim3(64), 0, stream,
                     counts, cursor, tmap_e, tmap_r);
  hipLaunchKernelGGL(kscatter, dim3(B_TOK), dim3(256), 0, stream,
                     x, ln_g, ln_b, meta_i, meta_f, cursor, slot_tok, slot_w, xe);
  hipLaunchKernelGGL(kgemm1, dim3(H_DIM / 128, MAXT), dim3(256), 0, stream,
                     xe, W1t, b1, hb, tmap_e, tmap_r);
  hipLaunchKernelGGL(kgemm2, dim3(C_DIM / 128, MAXT, 4), dim3(256), 0, stream,
                     hb, W2t, slot_tok, slot_w, out_acc, tmap_e, tmap_r);
  hipLaunchKernelGGL(kfinal, dim3(B_TOK), dim3(256), 0, stream,
                     out_acc, meta_i, meta_f, b2, (float*)d_out);
}

// Round 3
// 592.568 us; speedup vs baseline: 1.0174x; 1.0174x over previous
//
#include <hip/hip_runtime.h>
#include <hip/hip_bf16.h>

#define B_TOK 2048
#define D_DIM 1024
#define E_NUM 8
#define H_DIM 4096
#define C_DIM 1024
#define CAP   5120
#define MAXT  40
#define KZ    4

typedef __attribute__((ext_vector_type(8))) short bf16x8;
typedef __attribute__((ext_vector_type(4))) float floatx4;

__device__ __forceinline__ unsigned short f2bf(float f) {
  union { float f; unsigned int u; } a; a.f = f;
  unsigned int u = a.u;
  return (unsigned short)((u + 0x7FFFu + ((u >> 16) & 1u)) >> 16);
}

// Abramowitz-Stegun 7.1.26, |err| <= 1.5e-7 (well below bf16 rounding of h)
__device__ __forceinline__ float fast_erf(float x) {
  float ax = fabsf(x);
  float t = 1.f / fmaf(0.3275911f, ax, 1.f);
  float y = t * fmaf(t, fmaf(t, fmaf(t, fmaf(t, 1.061405429f, -1.453152027f),
                                     1.421413741f), -0.284496736f), 0.254829592f);
  float r = 1.f - y * __expf(-ax * ax);
  return copysignf(r, x);
}

__device__ __forceinline__ void gload_lds16(const void* g, void* l) {
  __builtin_amdgcn_global_load_lds(
      (const __attribute__((address_space(1))) void*)g,
      (__attribute__((address_space(3))) void*)l, 16, 0, 0);
}

// ---------------- router: logits, top2, softmax, LN stats ----------------
__global__ __launch_bounds__(256) void krouter(const float* __restrict__ x,
                                               const float* __restrict__ Wr,
                                               const float* __restrict__ br,
                                               int2* meta_i, float4* meta_f, int* counts) {
  int b = blockIdx.x, t = threadIdx.x;
  const float4 xv = *(const float4*)(x + (size_t)b * D_DIM + t * 4);
  float v[10];
  v[0] = xv.x + xv.y + xv.z + xv.w;
  v[1] = xv.x * xv.x + xv.y * xv.y + xv.z * xv.z + xv.w * xv.w;
#pragma unroll
  for (int e = 0; e < 8; e++) v[2 + e] = 0.f;
  const float* wr = Wr + (size_t)(t * 4) * E_NUM;
  float xs[4] = {xv.x, xv.y, xv.z, xv.w};
#pragma unroll
  for (int j = 0; j < 4; j++) {
    float4 wa = *(const float4*)(wr + j * 8);
    float4 wb = *(const float4*)(wr + j * 8 + 4);
    v[2] += xs[j] * wa.x; v[3] += xs[j] * wa.y; v[4] += xs[j] * wa.z; v[5] += xs[j] * wa.w;
    v[6] += xs[j] * wb.x; v[7] += xs[j] * wb.y; v[8] += xs[j] * wb.z; v[9] += xs[j] * wb.w;
  }
#pragma unroll
  for (int i = 0; i < 10; i++) {
    float s = v[i];
#pragma unroll
    for (int off = 32; off > 0; off >>= 1) s += __shfl_down(s, off, 64);
    v[i] = s;
  }
  __shared__ float red[4][10];
  int lane = t & 63, wid = t >> 6;
  if (lane == 0) {
#pragma unroll
    for (int i = 0; i < 10; i++) red[wid][i] = v[i];
  }
  __syncthreads();
  if (t == 0) {
    float f[10];
#pragma unroll
    for (int i = 0; i < 10; i++) f[i] = red[0][i] + red[1][i] + red[2][i] + red[3][i];
    float mu = f[0] * (1.f / 1024.f);
    float var = f[1] * (1.f / 1024.f) - mu * mu;
    float rsig = rsqrtf(var + 1e-5f);
    float lg[8];
#pragma unroll
    for (int e = 0; e < 8; e++) lg[e] = f[2 + e] + br[e];
    int i0 = 0;
#pragma unroll
    for (int e = 1; e < 8; e++) if (lg[e] > lg[i0]) i0 = e;
    int i1 = (i0 == 0) ? 1 : 0;
#pragma unroll
    for (int e = 0; e < 8; e++) if (e != i0 && lg[e] > lg[i1]) i1 = e;
    float ex = expf(lg[i1] - lg[i0]);       // <= 1
    float w0 = 1.f / (1.f + ex);
    float w1 = 1.f - w0;
    atomicAdd(counts + i0, 1);
    atomicAdd(counts + i1, 1);
    meta_i[b] = make_int2(i0, i1);
    meta_f[b] = make_float4(w0, w1, mu, rsig);
  }
}

// ---------------- prefix: 128-aligned segments + tile map ----------------
__global__ void kprefix(const int* counts, int* cursor, int* tmap_e, int* tmap_r) {
  if (threadIdx.x == 0) {
    int total = 0, tt = 0;
    for (int e = 0; e < E_NUM; e++) {
      cursor[e] = total;
      int nt = (counts[e] + 127) >> 7;
      for (int i = 0; i < nt; i++) { tmap_e[tt] = e; tmap_r[tt] = total + i * 128; tt++; }
      total += nt << 7;
    }
    for (; tt < MAXT; tt++) tmap_e[tt] = -1;
  }
}

// ---------------- scatter: slot assign + xe (bf16) + token->slot map ----------------
__global__ __launch_bounds__(256) void kscatter(const float* __restrict__ x,
                                                const float* __restrict__ ln_g,
                                                const float* __restrict__ ln_b,
                                                const int2* __restrict__ meta_i,
                                                const float4* __restrict__ meta_f,
                                                int* cursor, int2* meta_s,
                                                unsigned short* __restrict__ xe) {
  int b = blockIdx.x, t = threadIdx.x;
  __shared__ int se[2], ss[2];
  __shared__ float smu, srs;
  if (t == 0) {
    int2 mi = meta_i[b];
    float4 mf = meta_f[b];
    int s0 = atomicAdd(cursor + mi.x, 1);
    int s1 = atomicAdd(cursor + mi.y, 1);
    meta_s[b] = make_int2(s0, s1);
    se[0] = mi.x; se[1] = mi.y; ss[0] = s0; ss[1] = s1;
    smu = mf.z; srs = mf.w;
  }
  __syncthreads();
  int i = t * 4;
  float4 xv = *(const float4*)(x + (size_t)b * D_DIM + i);
  float mu = smu, rs = srs;
  float xn0 = (xv.x - mu) * rs, xn1 = (xv.y - mu) * rs, xn2 = (xv.z - mu) * rs, xn3 = (xv.w - mu) * rs;
#pragma unroll
  for (int k = 0; k < 2; k++) {
    int e = se[k], s = ss[k];
    float4 g = *(const float4*)(ln_g + (size_t)e * D_DIM + i);
    float4 bb = *(const float4*)(ln_b + (size_t)e * D_DIM + i);
    union { unsigned short us[4]; uint2 v; } u;
    u.us[0] = f2bf(xn0 * g.x + bb.x);
    u.us[1] = f2bf(xn1 * g.y + bb.y);
    u.us[2] = f2bf(xn2 * g.z + bb.z);
    u.us[3] = f2bf(xn3 * g.w + bb.w);
    *(uint2*)(xe + (size_t)s * D_DIM + i) = u.v;
  }
}

// ---------------- transpose+convert: src f32 [z][R][C] -> dst bf16 [z][C][R] ----------------
// 16B vector stores; first launch also zeroes counts (folds kinit away).
__global__ __launch_bounds__(256) void ktranspose(const float* __restrict__ src,
                                                  unsigned short* __restrict__ dst,
                                                  int R, int C, int* counts) {
  __shared__ float tile[64][65];
  int t = threadIdx.x;
  if (counts && blockIdx.x == 0 && blockIdx.y == 0 && blockIdx.z == 0 && t < E_NUM)
    counts[t] = 0;
  int z = blockIdx.z;
  const float* s = src + (size_t)z * R * C;
  unsigned short* d = dst + (size_t)z * R * C;
  int cx = blockIdx.x * 64, ry = blockIdx.y * 64;
  int cl4 = (t & 15) * 4, rl = t >> 4;
#pragma unroll
  for (int p = 0; p < 4; p++) {
    int r = rl + p * 16;
    float4 v = *(const float4*)(s + (size_t)(ry + r) * C + cx + cl4);
    tile[r][cl4] = v.x; tile[r][cl4 + 1] = v.y; tile[r][cl4 + 2] = v.z; tile[r][cl4 + 3] = v.w;
  }
  __syncthreads();
  int cg = t >> 3, r0 = (t & 7) * 8;
#pragma unroll
  for (int round = 0; round < 2; round++) {
    int c = cg + round * 32;
    union { unsigned short us[8]; uint4 v; } u;
#pragma unroll
    for (int j = 0; j < 8; j++) u.us[j] = f2bf(tile[r0 + j][c]);
    *(uint4*)(d + (size_t)(cx + c) * R + ry + r0) = u.v;
  }
}

// ---------------- GEMM1: h = gelu(xe @ W1[e] + b1[e]), bf16 out ----------------
// 128x128 tile, BK=32, SINGLE-buffered LDS (max blocks/CU TLP),
// XOR-swizzled LDS (pre-swizzled global source + swizzled ds_read), XCD swizzle.
__global__ __launch_bounds__(256) void kgemm1(const unsigned short* __restrict__ xe,
                                              const unsigned short* __restrict__ w1t,
                                              const float* __restrict__ b1,
                                              unsigned short* __restrict__ h,
                                              const int* __restrict__ tmap_e,
                                              const int* __restrict__ tmap_r) {
  // bijective XCD chunk remap: nwg = 32*40 = 1280, 1280/8 = 160
  int orig = blockIdx.y * 32 + blockIdx.x;
  int s = (orig & 7) * 160 + (orig >> 3);
  int bx = s & 31, by = s >> 5;
  int e = tmap_e[by];
  if (e < 0) return;
  int row0 = tmap_r[by];
  int n0 = bx * 128;
  const unsigned short* Ab = xe + (size_t)row0 * D_DIM;
  const unsigned short* Bb = w1t + (size_t)e * H_DIM * D_DIM + (size_t)n0 * D_DIM;
  __shared__ unsigned short As[128 * 32];
  __shared__ unsigned short Bs[128 * 32];
  int t = threadIdx.x, lane = t & 63, wid = t >> 6;
  int c0 = wid * 2, c1 = c0 + 1;
  int lr = lane >> 2;
  // source pre-swizzle: LDS slot (row, chunk=lane&3) receives global chunk (lane&3)^g(row),
  // g(row) = (row>>1)&3 = (lane>>3)&3 for row = cg*16 + (lane>>2)
  int kc = ((lane & 3) ^ ((lane >> 3) & 3)) * 8;
  const unsigned short* ga0 = Ab + (size_t)(c0 * 16 + lr) * D_DIM + kc;
  const unsigned short* ga1 = ga0 + 16 * D_DIM;
  const unsigned short* gb0 = Bb + (size_t)(c0 * 16 + lr) * D_DIM + kc;
  const unsigned short* gb1 = gb0 + 16 * D_DIM;
  unsigned short* la0 = As + c0 * 512;
  unsigned short* la1 = As + c1 * 512;
  unsigned short* lb0 = Bs + c0 * 512;
  unsigned short* lb1 = Bs + c1 * 512;
  int l15 = lane & 15, q = lane >> 4;
  int wm = (wid & 1) * 64, wn = (wid >> 1) * 64;
  int offA[4], offB[4];
#pragma unroll
  for (int i = 0; i < 4; i++) {
    int ra = wm + i * 16 + l15;
    int rb = wn + i * 16 + l15;
    offA[i] = ra * 32 + ((q ^ ((ra >> 1) & 3)) * 8);   // read-side swizzle (same XOR)
    offB[i] = rb * 32 + ((q ^ ((rb >> 1) & 3)) * 8);
  }
  floatx4 acc[4][4];
#pragma unroll
  for (int i = 0; i < 4; i++)
#pragma unroll
    for (int j = 0; j < 4; j++) acc[i][j] = (floatx4){0.f, 0.f, 0.f, 0.f};

  for (int k0 = 0; k0 < D_DIM; k0 += 32) {
    gload_lds16(ga0, la0);
    gload_lds16(ga1, la1);
    gload_lds16(gb0, lb0);
    gload_lds16(gb1, lb1);
    __syncthreads();
    bf16x8 af[4], bfr[4];
#pragma unroll
    for (int i = 0; i < 4; i++) { af[i] = *(const bf16x8*)(&As[offA[i]]); bfr[i] = *(const bf16x8*)(&Bs[offB[i]]); }
#pragma unroll
    for (int mt = 0; mt < 4; mt++)
#pragma unroll
      for (int nt = 0; nt < 4; nt++)
        acc[mt][nt] = __builtin_amdgcn_mfma_f32_16x16x32_bf16(af[mt], bfr[nt], acc[mt][nt], 0, 0, 0);
    __syncthreads();
    ga0 += 32; ga1 += 32; gb0 += 32; gb1 += 32;
  }
  float b1v[4];
#pragma unroll
  for (int nt = 0; nt < 4; nt++) b1v[nt] = b1[(size_t)e * H_DIM + n0 + wn + nt * 16 + l15];
#pragma unroll
  for (int mt = 0; mt < 4; mt++) {
    int row = row0 + wm + mt * 16 + q * 4;
#pragma unroll
    for (int nt = 0; nt < 4; nt++) {
      int col = n0 + wn + nt * 16 + l15;
      unsigned short* hp = h + (size_t)row * H_DIM + col;
#pragma unroll
      for (int r = 0; r < 4; r++) {
        float v = acc[mt][nt][r] + b1v[nt];
        v = 0.5f * v * (1.f + fast_erf(v * 0.70710678118f));
        hp[(size_t)r * H_DIM] = f2bf(v);
      }
    }
  }
}

// ---------------- GEMM2: y_parts[kz][slot] = h @ W2[e] (K-slice), plain stores ----------------
__global__ __launch_bounds__(256) void kgemm2(const unsigned short* __restrict__ h,
                                              const unsigned short* __restrict__ w2t,
                                              float* __restrict__ y_parts,
                                              const int* __restrict__ tmap_e,
                                              const int* __restrict__ tmap_r) {
  // bijective XCD chunk remap: nwg = 8*40*4 = 1280, 1280/8 = 160
  int orig = (blockIdx.z * MAXT + blockIdx.y) * 8 + blockIdx.x;
  int s = (orig & 7) * 160 + (orig >> 3);
  int bx = s & 7;
  int rest = s >> 3;
  int by = rest % MAXT;
  int kz = rest / MAXT;
  int e = tmap_e[by];
  if (e < 0) return;
  int row0 = tmap_r[by];
  int n0 = bx * 128;
  const unsigned short* Ab = h + (size_t)row0 * H_DIM + kz * 1024;
  const unsigned short* Bb = w2t + (size_t)e * C_DIM * H_DIM + (size_t)n0 * H_DIM + kz * 1024;
  __shared__ unsigned short As[128 * 32];
  __shared__ unsigned short Bs[128 * 32];
  int t = threadIdx.x, lane = t & 63, wid = t >> 6;
  int c0 = wid * 2, c1 = c0 + 1;
  int lr = lane >> 2;
  int kc = ((lane & 3) ^ ((lane >> 3) & 3)) * 8;
  const unsigned short* ga0 = Ab + (size_t)(c0 * 16 + lr) * H_DIM + kc;
  const unsigned short* ga1 = ga0 + (size_t)16 * H_DIM;
  const unsigned short* gb0 = Bb + (size_t)(c0 * 16 + lr) * H_DIM + kc;
  const unsigned short* gb1 = gb0 + (size_t)16 * H_DIM;
  unsigned short* la0 = As + c0 * 512;
  unsigned short* la1 = As + c1 * 512;
  unsigned short* lb0 = Bs + c0 * 512;
  unsigned short* lb1 = Bs + c1 * 512;
  int l15 = lane & 15, q = lane >> 4;
  int wm = (wid & 1) * 64, wn = (wid >> 1) * 64;
  int offA[4], offB[4];
#pragma unroll
  for (int i = 0; i < 4; i++) {
    int ra = wm + i * 16 + l15;
    int rb = wn + i * 16 + l15;
    offA[i] = ra * 32 + ((q ^ ((ra >> 1) & 3)) * 8);
    offB[i] = rb * 32 + ((q ^ ((rb >> 1) & 3)) * 8);
  }
  floatx4 acc[4][4];
#pragma unroll
  for (int i = 0; i < 4; i++)
#pragma unroll
    for (int j = 0; j < 4; j++) acc[i][j] = (floatx4){0.f, 0.f, 0.f, 0.f};

  for (int k0 = 0; k0 < 1024; k0 += 32) {
    gload_lds16(ga0, la0);
    gload_lds16(ga1, la1);
    gload_lds16(gb0, lb0);
    gload_lds16(gb1, lb1);
    __syncthreads();
    bf16x8 af[4], bfr[4];
#pragma unroll
    for (int i = 0; i < 4; i++) { af[i] = *(const bf16x8*)(&As[offA[i]]); bfr[i] = *(const bf16x8*)(&Bs[offB[i]]); }
#pragma unroll
    for (int mt = 0; mt < 4; mt++)
#pragma unroll
      for (int nt = 0; nt < 4; nt++)
        acc[mt][nt] = __builtin_amdgcn_mfma_f32_16x16x32_bf16(af[mt], bfr[nt], acc[mt][nt], 0, 0, 0);
    __syncthreads();
    ga0 += 32; ga1 += 32; gb0 += 32; gb1 += 32;
  }
  float* yp = y_parts + ((size_t)kz * CAP + row0) * C_DIM;
#pragma unroll
  for (int mt = 0; mt < 4; mt++) {
    int rbase = wm + mt * 16 + q * 4;
#pragma unroll
    for (int nt = 0; nt < 4; nt++) {
      int col = n0 + wn + nt * 16 + l15;
#pragma unroll
      for (int r = 0; r < 4; r++)
        yp[(size_t)(rbase + r) * C_DIM + col] = acc[mt][nt][r];
    }
  }
}

// ---------------- final: out = w0*(sum_kz y[s0]+b2[e0]) + w1*(sum_kz y[s1]+b2[e1]) ----------------
__global__ __launch_bounds__(256) void kfinal(const float* __restrict__ y_parts,
                                              const int2* __restrict__ meta_i,
                                              const int2* __restrict__ meta_s,
                                              const float4* __restrict__ meta_f,
                                              const float* __restrict__ b2,
                                              float* __restrict__ out) {
  int b = blockIdx.x, t = threadIdx.x;
  int i = t * 4;
  int2 mi = meta_i[b];
  int2 ms = meta_s[b];
  float4 mf = meta_f[b];
  float a0x = 0.f, a0y = 0.f, a0z = 0.f, a0w = 0.f;
  float a1x = 0.f, a1y = 0.f, a1z = 0.f, a1w = 0.f;
#pragma unroll
  for (int kz = 0; kz < KZ; kz++) {
    float4 p = *(const float4*)(y_parts + ((size_t)kz * CAP + ms.x) * C_DIM + i);
    float4 qv = *(const float4*)(y_parts + ((size_t)kz * CAP + ms.y) * C_DIM + i);
    a0x += p.x; a0y += p.y; a0z += p.z; a0w += p.w;
    a1x += qv.x; a1y += qv.y; a1z += qv.z; a1w += qv.w;
  }
  float4 p = *(const float4*)(b2 + (size_t)mi.x * C_DIM + i);
  float4 qv = *(const float4*)(b2 + (size_t)mi.y * C_DIM + i);
  float4 o;
  o.x = mf.x * (a0x + p.x) + mf.y * (a1x + qv.x);
  o.y = mf.x * (a0y + p.y) + mf.y * (a1y + qv.y);
  o.z = mf.x * (a0z + p.z) + mf.y * (a1z + qv.z);
  o.w = mf.x * (a0w + p.w) + mf.y * (a1w + qv.w);
  *(float4*)(out + (size_t)b * C_DIM + i) = o;
}

extern "C" void kernel_launch(void* const* d_in, const int* in_sizes, int n_in,
                              void* d_out, int out_size, void* d_ws, size_t ws_size,
                              hipStream_t stream) {
  const float* x    = (const float*)d_in[0];
  const float* Wr   = (const float*)d_in[1];
  const float* br   = (const float*)d_in[2];
  const float* ln_g = (const float*)d_in[3];
  const float* ln_b = (const float*)d_in[4];
  const float* W1   = (const float*)d_in[5];
  const float* b1   = (const float*)d_in[6];
  const float* W2   = (const float*)d_in[7];
  const float* b2   = (const float*)d_in[8];

  char* w = (char*)d_ws;
  auto alloc = [&](size_t sz) { char* p = w; w += (sz + 255) & ~(size_t)255; return p; };
  // y_parts aliases W1t: W1t (67.1 MB) is dead after kgemm1; y_parts (83.9 MB) written by
  // kgemm2 (after kgemm1 in stream order) and read by kfinal. Shared region = max of the two.
  size_t sz_w1t = (size_t)E_NUM * H_DIM * D_DIM * 2;
  size_t sz_yp  = (size_t)KZ * CAP * C_DIM * 4;
  char* shared_region = alloc(sz_yp > sz_w1t ? sz_yp : sz_w1t);
  unsigned short* W1t = (unsigned short*)shared_region;
  float* y_parts      = (float*)shared_region;
  unsigned short* W2t = (unsigned short*)alloc((size_t)E_NUM * C_DIM * H_DIM * 2);
  unsigned short* xe  = (unsigned short*)alloc((size_t)CAP * D_DIM * 2);
  unsigned short* hb  = (unsigned short*)alloc((size_t)CAP * H_DIM * 2);
  int2* meta_i        = (int2*)alloc((size_t)B_TOK * 8);
  float4* meta_f      = (float4*)alloc((size_t)B_TOK * 16);
  int2* meta_s        = (int2*)alloc((size_t)B_TOK * 8);
  int* counts         = (int*)alloc(64);
  int* cursor         = (int*)alloc(64);
  int* tmap_e         = (int*)alloc(MAXT * 4);
  int* tmap_r         = (int*)alloc(MAXT * 4);

  // transposes first (longest; independent of routing); first one zeroes counts
  hipLaunchKernelGGL(ktranspose, dim3(H_DIM / 64, D_DIM / 64, E_NUM), dim3(256), 0, stream,
                     W1, W1t, D_DIM, H_DIM, counts);
  hipLaunchKernelGGL(ktranspose, dim3(C_DIM / 64, H_DIM / 64, E_NUM), dim3(256), 0, stream,
                     W2, W2t, H_DIM, C_DIM, (int*)nullptr);
  hipLaunchKernelGGL(krouter, dim3(B_TOK), dim3(256), 0, stream,
                     x, Wr, br, meta_i, meta_f, counts);
  hipLaunchKernelGGL(kprefix, dim3(1), dim3(64), 0, stream,
                     counts, cursor, tmap_e, tmap_r);
  hipLaunchKernelGGL(kscatter, dim3(B_TOK), dim3(256), 0, stream,
                     x, ln_g, ln_b, meta_i, meta_f, cursor, meta_s, xe);
  hipLaunchKernelGGL(kgemm1, dim3(H_DIM / 128, MAXT), dim3(256), 0, stream,
                     xe, W1t, b1, hb, tmap_e, tmap_r);
  hipLaunchKernelGGL(kgemm2, dim3(C_DIM / 128, MAXT, KZ), dim3(256), 0, stream,
                     hb, W2t, y_parts, tmap_e, tmap_r);
  hipLaunchKernelGGL(kfinal, dim3(B_TOK), dim3(256), 0, stream,
                     y_parts, meta_i, meta_s, meta_f, b2, (float*)d_out);
}

// Round 5
// 548.423 us; speedup vs baseline: 1.0993x; 1.0805x over previous
//
#include <hip/hip_runtime.h>
#include <hip/hip_bf16.h>

#define B_TOK 2048
#define D_DIM 1024
#define E_NUM 8
#define H_DIM 4096
#define C_DIM 1024
#define ESTR  768          // per-expert slot-region stride (6 tiles of 128)
#define CAP   (E_NUM * ESTR)   // 6144
#define NTIL  (CAP / 128)      // 48 tile-rows
#define KZ    2

typedef __attribute__((ext_vector_type(8))) short bf16x8;
typedef __attribute__((ext_vector_type(4))) float floatx4;

__device__ __forceinline__ unsigned short f2bf(float f) {
  union { float f; unsigned int u; } a; a.f = f;
  unsigned int u = a.u;
  return (unsigned short)((u + 0x7FFFu + ((u >> 16) & 1u)) >> 16);
}

// Abramowitz-Stegun 7.1.26, |err| <= 1.5e-7 (well below bf16 rounding of h)
__device__ __forceinline__ float fast_erf(float x) {
  float ax = fabsf(x);
  float t = 1.f / fmaf(0.3275911f, ax, 1.f);
  float y = t * fmaf(t, fmaf(t, fmaf(t, fmaf(t, 1.061405429f, -1.453152027f),
                                     1.421413741f), -0.284496736f), 0.254829592f);
  float r = 1.f - y * __expf(-ax * ax);
  return copysignf(r, x);
}

__device__ __forceinline__ void gload_lds16(const void* g, void* l) {
  __builtin_amdgcn_global_load_lds(
      (const __attribute__((address_space(1))) void*)g,
      (__attribute__((address_space(3))) void*)l, 16, 0, 0);
}

// ---------------- unified weight transpose+convert (W1 and W2 in one launch) ----
// id < 8192: W1 slice (R=D, C=H) -> W1t [E][H][D]; else W2 slice (R=H, C=C) -> W2t [E][C][H]
__global__ __launch_bounds__(256) void ktransw(const float* __restrict__ W1,
                                               const float* __restrict__ W2,
                                               unsigned short* __restrict__ W1t,
                                               unsigned short* __restrict__ W2t,
                                               int* counts) {
  __shared__ float tile[64][65];
  int id = blockIdx.x, t = threadIdx.x;
  if (id == 0 && t < E_NUM) counts[t] = 0;
  int z = id >> 10, sub = id & 1023;
  const float* src; unsigned short* dst; int R, C, ct, rt;
  if (z < E_NUM) {
    R = D_DIM; C = H_DIM;
    src = W1 + (size_t)z * R * C;
    dst = W1t + (size_t)z * R * C;
    ct = sub & 63; rt = sub >> 6;            // 64 c-tiles x 16 r-tiles
  } else {
    int z2 = z - E_NUM;
    R = H_DIM; C = C_DIM;
    src = W2 + (size_t)z2 * R * C;
    dst = W2t + (size_t)z2 * R * C;
    ct = sub & 15; rt = sub >> 4;            // 16 c-tiles x 64 r-tiles
  }
  int cx = ct * 64, ry = rt * 64;
  int cl4 = (t & 15) * 4, rl = t >> 4;
#pragma unroll
  for (int p = 0; p < 4; p++) {
    int r = rl + p * 16;
    float4 v = *(const float4*)(src + (size_t)(ry + r) * C + cx + cl4);
    tile[r][cl4] = v.x; tile[r][cl4 + 1] = v.y; tile[r][cl4 + 2] = v.z; tile[r][cl4 + 3] = v.w;
  }
  __syncthreads();
  int cg = t >> 3, r0 = (t & 7) * 8;
#pragma unroll
  for (int round = 0; round < 2; round++) {
    int c = cg + round * 32;
    union { unsigned short us[8]; uint4 v; } u;
#pragma unroll
    for (int j = 0; j < 8; j++) u.us[j] = f2bf(tile[r0 + j][c]);
    *(uint4*)(dst + (size_t)(cx + c) * R + ry + r0) = u.v;
  }
}

// ---------------- fused router + LN + scatter (per-token, no cross-block deps) ----
__global__ __launch_bounds__(256) void krs(const float* __restrict__ x,
                                           const float* __restrict__ Wr,
                                           const float* __restrict__ br,
                                           const float* __restrict__ ln_g,
                                           const float* __restrict__ ln_b,
                                           int* counts,
                                           int2* __restrict__ meta_i,
                                           int2* __restrict__ meta_s,
                                           float2* __restrict__ meta_w,
                                           unsigned short* __restrict__ xe) {
  int b = blockIdx.x, t = threadIdx.x;
  const float4 xv = *(const float4*)(x + (size_t)b * D_DIM + t * 4);
  float v[10];
  v[0] = xv.x + xv.y + xv.z + xv.w;
  v[1] = xv.x * xv.x + xv.y * xv.y + xv.z * xv.z + xv.w * xv.w;
#pragma unroll
  for (int e = 0; e < 8; e++) v[2 + e] = 0.f;
  const float* wr = Wr + (size_t)(t * 4) * E_NUM;
  float xs[4] = {xv.x, xv.y, xv.z, xv.w};
#pragma unroll
  for (int j = 0; j < 4; j++) {
    float4 wa = *(const float4*)(wr + j * 8);
    float4 wb = *(const float4*)(wr + j * 8 + 4);
    v[2] += xs[j] * wa.x; v[3] += xs[j] * wa.y; v[4] += xs[j] * wa.z; v[5] += xs[j] * wa.w;
    v[6] += xs[j] * wb.x; v[7] += xs[j] * wb.y; v[8] += xs[j] * wb.z; v[9] += xs[j] * wb.w;
  }
#pragma unroll
  for (int i = 0; i < 10; i++) {
    float s = v[i];
#pragma unroll
    for (int off = 32; off > 0; off >>= 1) s += __shfl_down(s, off, 64);
    v[i] = s;
  }
  __shared__ float red[4][10];
  __shared__ int se[2], ss[2];
  __shared__ float smu, srs;
  int lane = t & 63, wid = t >> 6;
  if (lane == 0) {
#pragma unroll
    for (int i = 0; i < 10; i++) red[wid][i] = v[i];
  }
  __syncthreads();
  if (t == 0) {
    float f[10];
#pragma unroll
    for (int i = 0; i < 10; i++) f[i] = red[0][i] + red[1][i] + red[2][i] + red[3][i];
    float mu = f[0] * (1.f / 1024.f);
    float var = f[1] * (1.f / 1024.f) - mu * mu;
    float rsig = rsqrtf(var + 1e-5f);
    float lg[8];
#pragma unroll
    for (int e = 0; e < 8; e++) lg[e] = f[2 + e] + br[e];
    int i0 = 0;
#pragma unroll
    for (int e = 1; e < 8; e++) if (lg[e] > lg[i0]) i0 = e;
    int i1 = (i0 == 0) ? 1 : 0;
#pragma unroll
    for (int e = 0; e < 8; e++) if (e != i0 && lg[e] > lg[i1]) i1 = e;
    float ex = expf(lg[i1] - lg[i0]);       // <= 1
    float w0 = 1.f / (1.f + ex);
    float w1 = 1.f - w0;
    int s0 = i0 * ESTR + atomicAdd(counts + i0, 1);
    int s1 = i1 * ESTR + atomicAdd(counts + i1, 1);
    meta_i[b] = make_int2(i0, i1);
    meta_s[b] = make_int2(s0, s1);
    meta_w[b] = make_float2(w0, w1);
    se[0] = i0; se[1] = i1; ss[0] = s0; ss[1] = s1;
    smu = mu; srs = rsig;
  }
  __syncthreads();
  int i = t * 4;
  float mu = smu, rs = srs;
  float xn0 = (xv.x - mu) * rs, xn1 = (xv.y - mu) * rs, xn2 = (xv.z - mu) * rs, xn3 = (xv.w - mu) * rs;
#pragma unroll
  for (int k = 0; k < 2; k++) {
    int e = se[k], s = ss[k];
    float4 g = *(const float4*)(ln_g + (size_t)e * D_DIM + i);
    float4 bb = *(const float4*)(ln_b + (size_t)e * D_DIM + i);
    union { unsigned short us[4]; uint2 v; } u;
    u.us[0] = f2bf(xn0 * g.x + bb.x);
    u.us[1] = f2bf(xn1 * g.y + bb.y);
    u.us[2] = f2bf(xn2 * g.z + bb.z);
    u.us[3] = f2bf(xn3 * g.w + bb.w);
    *(uint2*)(xe + (size_t)s * D_DIM + i) = u.v;
  }
}

// ---------------- GEMM1: h = gelu(xe @ W1[e] + b1[e]), bf16 out ----------------
// 128x128 tile, BK=32, single-buffered LDS, XOR-swizzled (0 bank conflicts), XCD swizzle.
// Fixed grid: by in [0,48) -> expert by/6, tile (by%6); early-exit on empty tile.
__global__ __launch_bounds__(256) void kgemm1(const unsigned short* __restrict__ xe,
                                              const unsigned short* __restrict__ w1t,
                                              const float* __restrict__ b1,
                                              unsigned short* __restrict__ h,
                                              const int* __restrict__ counts) {
  // bijective XCD chunk remap: nwg = 32*48 = 1536, 1536/8 = 192
  int orig = blockIdx.y * 32 + blockIdx.x;
  int s = (orig & 7) * 192 + (orig >> 3);
  int bx = s & 31, by = s >> 5;
  int e = by / 6, ti = by - e * 6;
  if (ti * 128 >= counts[e]) return;
  int row0 = e * ESTR + ti * 128;
  int n0 = bx * 128;
  const unsigned short* Ab = xe + (size_t)row0 * D_DIM;
  const unsigned short* Bb = w1t + (size_t)e * H_DIM * D_DIM + (size_t)n0 * D_DIM;
  __shared__ unsigned short As[128 * 32];
  __shared__ unsigned short Bs[128 * 32];
  int t = threadIdx.x, lane = t & 63, wid = t >> 6;
  int c0 = wid * 2, c1 = c0 + 1;
  int lr = lane >> 2;
  // source pre-swizzle: LDS slot (row, chunk=lane&3) receives global chunk (lane&3)^g(row),
  // g(row) = (row>>1)&3 = (lane>>3)&3 for row = cg*16 + (lane>>2)
  int kc = ((lane & 3) ^ ((lane >> 3) & 3)) * 8;
  const unsigned short* ga0 = Ab + (size_t)(c0 * 16 + lr) * D_DIM + kc;
  const unsigned short* ga1 = ga0 + 16 * D_DIM;
  const unsigned short* gb0 = Bb + (size_t)(c0 * 16 + lr) * D_DIM + kc;
  const unsigned short* gb1 = gb0 + 16 * D_DIM;
  unsigned short* la0 = As + c0 * 512;
  unsigned short* la1 = As + c1 * 512;
  unsigned short* lb0 = Bs + c0 * 512;
  unsigned short* lb1 = Bs + c1 * 512;
  int l15 = lane & 15, q = lane >> 4;
  int wm = (wid & 1) * 64, wn = (wid >> 1) * 64;
  int offA[4], offB[4];
#pragma unroll
  for (int i = 0; i < 4; i++) {
    int ra = wm + i * 16 + l15;
    int rb = wn + i * 16 + l15;
    offA[i] = ra * 32 + ((q ^ ((ra >> 1) & 3)) * 8);   // read-side swizzle (same XOR)
    offB[i] = rb * 32 + ((q ^ ((rb >> 1) & 3)) * 8);
  }
  floatx4 acc[4][4];
#pragma unroll
  for (int i = 0; i < 4; i++)
#pragma unroll
    for (int j = 0; j < 4; j++) acc[i][j] = (floatx4){0.f, 0.f, 0.f, 0.f};

  for (int k0 = 0; k0 < D_DIM; k0 += 32) {
    gload_lds16(ga0, la0);
    gload_lds16(ga1, la1);
    gload_lds16(gb0, lb0);
    gload_lds16(gb1, lb1);
    __syncthreads();
    bf16x8 af[4], bfr[4];
#pragma unroll
    for (int i = 0; i < 4; i++) { af[i] = *(const bf16x8*)(&As[offA[i]]); bfr[i] = *(const bf16x8*)(&Bs[offB[i]]); }
#pragma unroll
    for (int mt = 0; mt < 4; mt++)
#pragma unroll
      for (int nt = 0; nt < 4; nt++)
        acc[mt][nt] = __builtin_amdgcn_mfma_f32_16x16x32_bf16(af[mt], bfr[nt], acc[mt][nt], 0, 0, 0);
    __syncthreads();
    ga0 += 32; ga1 += 32; gb0 += 32; gb1 += 32;
  }
  float b1v[4];
#pragma unroll
  for (int nt = 0; nt < 4; nt++) b1v[nt] = b1[(size_t)e * H_DIM + n0 + wn + nt * 16 + l15];
#pragma unroll
  for (int mt = 0; mt < 4; mt++) {
    int row = row0 + wm + mt * 16 + q * 4;
#pragma unroll
    for (int nt = 0; nt < 4; nt++) {
      int col = n0 + wn + nt * 16 + l15;
      unsigned short* hp = h + (size_t)row * H_DIM + col;
#pragma unroll
      for (int r = 0; r < 4; r++) {
        float v = acc[mt][nt][r] + b1v[nt];
        v = 0.5f * v * (1.f + fast_erf(v * 0.70710678118f));
        hp[(size_t)r * H_DIM] = f2bf(v);
      }
    }
  }
}

// ---------------- GEMM2: y_parts[kz][slot] = h @ W2[e] (K-slice), plain stores ----
__global__ __launch_bounds__(256) void kgemm2(const unsigned short* __restrict__ h,
                                              const unsigned short* __restrict__ w2t,
                                              float* __restrict__ y_parts,
                                              const int* __restrict__ counts) {
  // bijective XCD chunk remap: nwg = 8*48*2 = 768, 768/8 = 96
  int orig = (blockIdx.z * NTIL + blockIdx.y) * 8 + blockIdx.x;
  int s = (orig & 7) * 96 + (orig >> 3);
  int bx = s & 7;
  int rest = s >> 3;
  int by = rest % NTIL;
  int kz = rest / NTIL;
  int e = by / 6, ti = by - e * 6;
  if (ti * 128 >= counts[e]) return;
  int row0 = e * ESTR + ti * 128;
  int n0 = bx * 128;
  const unsigned short* Ab = h + (size_t)row0 * H_DIM + kz * 2048;
  const unsigned short* Bb = w2t + (size_t)e * C_DIM * H_DIM + (size_t)n0 * H_DIM + kz * 2048;
  __shared__ unsigned short As[128 * 32];
  __shared__ unsigned short Bs[128 * 32];
  int t = threadIdx.x, lane = t & 63, wid = t >> 6;
  int c0 = wid * 2, c1 = c0 + 1;
  int lr = lane >> 2;
  int kc = ((lane & 3) ^ ((lane >> 3) & 3)) * 8;
  const unsigned short* ga0 = Ab + (size_t)(c0 * 16 + lr) * H_DIM + kc;
  const unsigned short* ga1 = ga0 + (size_t)16 * H_DIM;
  const unsigned short* gb0 = Bb + (size_t)(c0 * 16 + lr) * H_DIM + kc;
  const unsigned short* gb1 = gb0 + (size_t)16 * H_DIM;
  unsigned short* la0 = As + c0 * 512;
  unsigned short* la1 = As + c1 * 512;
  unsigned short* lb0 = Bs + c0 * 512;
  unsigned short* lb1 = Bs + c1 * 512;
  int l15 = lane & 15, q = lane >> 4;
  int wm = (wid & 1) * 64, wn = (wid >> 1) * 64;
  int offA[4], offB[4];
#pragma unroll
  for (int i = 0; i < 4; i++) {
    int ra = wm + i * 16 + l15;
    int rb = wn + i * 16 + l15;
    offA[i] = ra * 32 + ((q ^ ((ra >> 1) & 3)) * 8);
    offB[i] = rb * 32 + ((q ^ ((rb >> 1) & 3)) * 8);
  }
  floatx4 acc[4][4];
#pragma unroll
  for (int i = 0; i < 4; i++)
#pragma unroll
    for (int j = 0; j < 4; j++) acc[i][j] = (floatx4){0.f, 0.f, 0.f, 0.f};

  for (int k0 = 0; k0 < 2048; k0 += 32) {
    gload_lds16(ga0, la0);
    gload_lds16(ga1, la1);
    gload_lds16(gb0, lb0);
    gload_lds16(gb1, lb1);
    __syncthreads();
    bf16x8 af[4], bfr[4];
#pragma unroll
    for (int i = 0; i < 4; i++) { af[i] = *(const bf16x8*)(&As[offA[i]]); bfr[i] = *(const bf16x8*)(&Bs[offB[i]]); }
#pragma unroll
    for (int mt = 0; mt < 4; mt++)
#pragma unroll
      for (int nt = 0; nt < 4; nt++)
        acc[mt][nt] = __builtin_amdgcn_mfma_f32_16x16x32_bf16(af[mt], bfr[nt], acc[mt][nt], 0, 0, 0);
    __syncthreads();
    ga0 += 32; ga1 += 32; gb0 += 32; gb1 += 32;
  }
  float* yp = y_parts + ((size_t)kz * CAP + row0) * C_DIM;
#pragma unroll
  for (int mt = 0; mt < 4; mt++) {
    int rbase = wm + mt * 16 + q * 4;
#pragma unroll
    for (int nt = 0; nt < 4; nt++) {
      int col = n0 + wn + nt * 16 + l15;
#pragma unroll
      for (int r = 0; r < 4; r++)
        yp[(size_t)(rbase + r) * C_DIM + col] = acc[mt][nt][r];
    }
  }
}

// ---------------- final: out = w0*(sum_kz y[s0]+b2[e0]) + w1*(sum_kz y[s1]+b2[e1]) ----
__global__ __launch_bounds__(256) void kfinal(const float* __restrict__ y_parts,
                                              const int2* __restrict__ meta_i,
                                              const int2* __restrict__ meta_s,
                                              const float2* __restrict__ meta_w,
                                              const float* __restrict__ b2,
                                              float* __restrict__ out) {
  int b = blockIdx.x, t = threadIdx.x;
  int i = t * 4;
  int2 mi = meta_i[b];
  int2 ms = meta_s[b];
  float2 mw = meta_w[b];
  float a0x = 0.f, a0y = 0.f, a0z = 0.f, a0w = 0.f;
  float a1x = 0.f, a1y = 0.f, a1z = 0.f, a1w = 0.f;
#pragma unroll
  for (int kz = 0; kz < KZ; kz++) {
    float4 p = *(const float4*)(y_parts + ((size_t)kz * CAP + ms.x) * C_DIM + i);
    float4 qv = *(const float4*)(y_parts + ((size_t)kz * CAP + ms.y) * C_DIM + i);
    a0x += p.x; a0y += p.y; a0z += p.z; a0w += p.w;
    a1x += qv.x; a1y += qv.y; a1z += qv.z; a1w += qv.w;
  }
  float4 p = *(const float4*)(b2 + (size_t)mi.x * C_DIM + i);
  float4 qv = *(const float4*)(b2 + (size_t)mi.y * C_DIM + i);
  float4 o;
  o.x = mw.x * (a0x + p.x) + mw.y * (a1x + qv.x);
  o.y = mw.x * (a0y + p.y) + mw.y * (a1y + qv.y);
  o.z = mw.x * (a0z + p.z) + mw.y * (a1z + qv.z);
  o.w = mw.x * (a0w + p.w) + mw.y * (a1w + qv.w);
  *(float4*)(out + (size_t)b * C_DIM + i) = o;
}

extern "C" void kernel_launch(void* const* d_in, const int* in_sizes, int n_in,
                              void* d_out, int out_size, void* d_ws, size_t ws_size,
                              hipStream_t stream) {
  const float* x    = (const float*)d_in[0];
  const float* Wr   = (const float*)d_in[1];
  const float* br   = (const float*)d_in[2];
  const float* ln_g = (const float*)d_in[3];
  const float* ln_b = (const float*)d_in[4];
  const float* W1   = (const float*)d_in[5];
  const float* b1   = (const float*)d_in[6];
  const float* W2   = (const float*)d_in[7];
  const float* b2   = (const float*)d_in[8];

  char* w = (char*)d_ws;
  auto alloc = [&](size_t sz) { char* p = w; w += (sz + 255) & ~(size_t)255; return p; };
  // y_parts (KZ*CAP*C*4 = 50.3 MB) aliases W1t (67.1 MB): W1t dead after kgemm1;
  // y_parts written by kgemm2 and read by kfinal (both after kgemm1 in stream order).
  size_t sz_w1t = (size_t)E_NUM * H_DIM * D_DIM * 2;
  size_t sz_yp  = (size_t)KZ * CAP * C_DIM * 4;
  char* shared_region = alloc(sz_yp > sz_w1t ? sz_yp : sz_w1t);
  unsigned short* W1t = (unsigned short*)shared_region;
  float* y_parts      = (float*)shared_region;
  unsigned short* W2t = (unsigned short*)alloc((size_t)E_NUM * C_DIM * H_DIM * 2);
  unsigned short* xe  = (unsigned short*)alloc((size_t)CAP * D_DIM * 2);
  unsigned short* hb  = (unsigned short*)alloc((size_t)CAP * H_DIM * 2);
  int2* meta_i        = (int2*)alloc((size_t)B_TOK * 8);
  int2* meta_s        = (int2*)alloc((size_t)B_TOK * 8);
  float2* meta_w      = (float2*)alloc((size_t)B_TOK * 8);
  int* counts         = (int*)alloc(64);

  // 5-kernel pipeline: full rocprof top-5 visibility
  hipLaunchKernelGGL(ktransw, dim3(16384), dim3(256), 0, stream,
                     W1, W2, W1t, W2t, counts);
  hipLaunchKernelGGL(krs, dim3(B_TOK), dim3(256), 0, stream,
                     x, Wr, br, ln_g, ln_b, counts, meta_i, meta_s, meta_w, xe);
  hipLaunchKernelGGL(kgemm1, dim3(H_DIM / 128, NTIL), dim3(256), 0, stream,
                     xe, W1t, b1, hb, counts);
  hipLaunchKernelGGL(kgemm2, dim3(C_DIM / 128, NTIL, KZ), dim3(256), 0, stream,
                     hb, W2t, y_parts, counts);
  hipLaunchKernelGGL(kfinal, dim3(B_TOK), dim3(256), 0, stream,
                     y_parts, meta_i, meta_s, meta_w, b2, (float*)d_out);
}